// Round 7
// baseline (6838.454 us; speedup 1.0000x reference)
//
#include <hip/hip_runtime.h>
#include <hip/hip_bf16.h>

#define BB 64
#define TT 128
#define FF 2048
#define HH 1024
#define CC 22
#define G4 4096      // 4*H
#define KD 2048      // decoder Z inner dim (attn | h)
#define BT 8192      // B*T

typedef __attribute__((ext_vector_type(8))) short bf16x8;
typedef __attribute__((ext_vector_type(4))) float f32x4;

__device__ __forceinline__ f32x4 mfma16(bf16x8 a, bf16x8 b, f32x4 c) {
    return __builtin_amdgcn_mfma_f32_16x16x32_bf16(a, b, c, 0, 0, 0);
}

__device__ __forceinline__ float b2f(short s) {
    unsigned int u = ((unsigned int)(unsigned short)s) << 16;
    union { unsigned int i; float f; } x; x.i = u; return x.f;
}

__device__ __forceinline__ short f2bs(float f) {
    union { __hip_bfloat16 h; short s; } u;
    u.h = __float2bfloat16(f);
    return u.s;
}

// ---------------- utility kernels ----------------

__global__ void zero_u32(unsigned int* p, long long n) {
    long long i = (long long)blockIdx.x * 256 + threadIdx.x;
    if (i < n) p[i] = 0u;
}

__global__ void fill_f32(float* p, long long n, float v) {
    long long i = (long long)blockIdx.x * 256 + threadIdx.x;
    if (i < n) p[i] = v;
}

// dst[r*dld + c] = bf16(src[r*sld + soff + c]) for r < valid, else 0
__global__ void pack_bf16(const float* __restrict__ src, long long sld, long long soff,
                          __hip_bfloat16* __restrict__ dst, long long dld,
                          int rows, int cols, int valid) {
    long long i = (long long)blockIdx.x * 256 + threadIdx.x;
    long long tot = (long long)rows * cols;
    if (i >= tot) return;
    int r = (int)(i / cols), c = (int)(i % cols);
    float v = (r < valid) ? src[(long long)r * sld + soff + c] : 0.f;
    dst[(long long)r * dld + c] = __float2bfloat16(v);
}

// dst[c*R + r] = bf16(src[r*C + c])   (transpose-convert)
__global__ void packT_bf16(const float* __restrict__ src, int R, int Ccols,
                           __hip_bfloat16* __restrict__ dst) {
    long long i = (long long)blockIdx.x * 256 + threadIdx.x;
    long long tot = (long long)R * Ccols;
    if (i >= tot) return;
    int r = (int)(i / Ccols), c = (int)(i % Ccols);
    dst[(long long)c * R + r] = __float2bfloat16(src[i]);
}

__global__ void add_bias2(const float* a, const float* b, float* out, int n) {
    int i = blockIdx.x * 256 + threadIdx.x;
    if (i < n) out[i] = a[i] + b[i];
}

__global__ void pad_bias(const float* src, float* dst, int nsrc, int ndst) {
    int i = blockIdx.x * blockDim.x + threadIdx.x;
    if (i < ndst) dst[i] = (i < nsrc) ? src[i] : 0.f;
}

// badd[r] = dbih[r] + dbhh[r] + dot(dec_Wih[r, F:F+H], bd2e)
__global__ __launch_bounds__(64) void bcomb_kernel(const float* __restrict__ dWih,
                                                   const float* __restrict__ bd2e,
                                                   const float* __restrict__ dbih,
                                                   const float* __restrict__ dbhh,
                                                   float* __restrict__ badd) {
    int r = blockIdx.x, lane = threadIdx.x;
    const float* row = dWih + (long long)r * (FF + HH) + FF;
    float s = 0.f;
    for (int k = lane; k < HH; k += 64) s += row[k] * bd2e[k];
    #pragma unroll
    for (int off = 32; off; off >>= 1) s += __shfl_xor(s, off, 64);
    if (lane == 0) badd[r] = s + dbih[r] + dbhh[r];
}

// ---------------- MFMA GEMM: C[M,N] = A[M,K] @ W[N,K]^T (+bias) ----------------
// block = 256 thr (4 waves), block tile 128x128, wave tile 64x64 (4x4 of 16x16).
// AF32: A is fp32 with leading dim lda, vector-loaded (float4 x2) and converted.
template <int K, bool AF32>
__global__ __launch_bounds__(256) void gemm_tile(
    const void* __restrict__ Aptr, long long lda,
    const __hip_bfloat16* __restrict__ W,
    const float* __restrict__ bias, void* __restrict__ Cout, int out_bf16,
    long long ldc, int n_store) {
    int tid = threadIdx.x;
    int wave = tid >> 6, lane = tid & 63;
    int wm = wave >> 1, wn = wave & 1;
    int m_base = blockIdx.x * 128 + wm * 64;
    int n_base = blockIdx.y * 128 + wn * 64;
    int row_in = lane & 15, k8 = (lane >> 4) * 8;

    f32x4 acc[4][4] = {};
    const float* Af = (const float*)Aptr + (long long)(m_base + row_in) * lda + k8;
    const __hip_bfloat16* Ab = (const __hip_bfloat16*)Aptr + (long long)(m_base + row_in) * lda + k8;
    const __hip_bfloat16* Wp = W + (long long)(n_base + row_in) * K + k8;

    #pragma unroll 2
    for (int k0 = 0; k0 < K; k0 += 32) {
        bf16x8 a[4], b[4];
        #pragma unroll
        for (int i = 0; i < 4; i++) {
            if (AF32) {
                const float* p = Af + (long long)i * 16 * lda + k0;
                const float4 f0 = *(const float4*)(p);
                const float4 f1 = *(const float4*)(p + 4);
                a[i][0] = f2bs(f0.x); a[i][1] = f2bs(f0.y);
                a[i][2] = f2bs(f0.z); a[i][3] = f2bs(f0.w);
                a[i][4] = f2bs(f1.x); a[i][5] = f2bs(f1.y);
                a[i][6] = f2bs(f1.z); a[i][7] = f2bs(f1.w);
            } else {
                a[i] = *(const bf16x8*)(Ab + (long long)i * 16 * lda + k0);
            }
        }
        #pragma unroll
        for (int i = 0; i < 4; i++) b[i] = *(const bf16x8*)(Wp + (long long)i * 16 * K + k0);
        #pragma unroll
        for (int mt = 0; mt < 4; mt++)
            #pragma unroll
            for (int nt = 0; nt < 4; nt++)
                acc[mt][nt] = mfma16(a[mt], b[nt], acc[mt][nt]);
    }

    int col = lane & 15, rowq = (lane >> 4) * 4;
    #pragma unroll
    for (int mt = 0; mt < 4; mt++)
        #pragma unroll
        for (int nt = 0; nt < 4; nt++) {
            int n = n_base + nt * 16 + col;
            if (n >= n_store) continue;
            float bv = bias ? bias[n] : 0.f;
            #pragma unroll
            for (int r = 0; r < 4; r++) {
                long long m = m_base + mt * 16 + rowq + r;
                float v = acc[mt][nt][r] + bv;
                if (out_bf16) ((__hip_bfloat16*)Cout)[m * ldc + n] = __float2bfloat16(v);
                else          ((float*)Cout)[m * ldc + n] = v;
            }
        }
}

// ---------------- fused gates GEMM + LSTM cell update ----------------
// Grid: 256 blocks = 64 hh-tiles x 4 batch-quarters; block 1024 thr = 16 waves = 4g x 4ks.
// Wave: 16x16 MFMA tile over K/4; partials reduced through LDS; 256 epilogue threads.
// Reads Z (prev h) and writes new h -> caller MUST ping-pong h/Z buffers.
template <int KZ>
__global__ __launch_bounds__(1024) void fused_step(
    const __hip_bfloat16* __restrict__ Z,        // [64, KZ]
    const __hip_bfloat16* __restrict__ W,        // [4096, KZ]
    const __hip_bfloat16* __restrict__ Xg_t, long long xg_stride,
    float* __restrict__ c,
    float* __restrict__ h_f32,
    __hip_bfloat16* __restrict__ hb_a, long long stride_a,
    __hip_bfloat16* __restrict__ hb_b, long long stride_b) {
    constexpr int KQ = KZ / 4;
    __shared__ float P[16 * 256];
    int tid = threadIdx.x;
    int wave = tid >> 6, lane = tid & 63;
    int g = wave >> 2, ks = wave & 3;
    int hh_t = blockIdx.x & 63, mb = blockIdx.x >> 6;
    int m_base = mb * 16;
    int hh0 = hh_t * 16;
    int n0 = g * HH + hh0;
    int row_in = lane & 15, k8 = (lane >> 4) * 8;
    long long koff = (long long)ks * KQ + k8;

    const __hip_bfloat16* Ap = Z + (long long)(m_base + row_in) * KZ + koff;
    const __hip_bfloat16* Wp = W + (long long)(n0 + row_in) * KZ + koff;

    f32x4 acc = {};
    #pragma unroll 8
    for (int k0 = 0; k0 < KQ; k0 += 32) {
        bf16x8 bw = *(const bf16x8*)(Wp + k0);
        bf16x8 a0 = *(const bf16x8*)(Ap + k0);
        acc = mfma16(a0, bw, acc);
    }

    int col = lane & 15, rowq = (lane >> 4) * 4;
    #pragma unroll
    for (int r = 0; r < 4; r++)
        P[wave * 256 + (rowq + r) * 16 + col] = acc[r];
    __syncthreads();

    if (tid < 256) {
        int bl = tid >> 4, hl = tid & 15;
        int bb = m_base + bl, hh = hh0 + hl;
        float gv[4];
        #pragma unroll
        for (int gg2 = 0; gg2 < 4; gg2++) {
            float s = 0.f;
            #pragma unroll
            for (int kk = 0; kk < 4; kk++) s += P[(gg2 * 4 + kk) * 256 + tid];
            gv[gg2] = s + __bfloat162float(Xg_t[(long long)bb * xg_stride + gg2 * HH + hh]);
        }
        float si = 1.f / (1.f + __expf(-gv[0]));
        float sf = 1.f / (1.f + __expf(-gv[1]));
        float tg = tanhf(gv[2]);
        float so = 1.f / (1.f + __expf(-gv[3]));
        long long idx = (long long)bb * HH + hh;
        float cn = sf * c[idx] + si * tg;
        c[idx] = cn;
        float hn = so * tanhf(cn);
        if (h_f32) h_f32[idx] = hn;
        __hip_bfloat16 hb = __float2bfloat16(hn);
        hb_a[(long long)bb * stride_a + hh] = hb;
        hb_b[(long long)bb * stride_b + hh] = hb;
    }
}

// ---------------- single-dispatch attention, NON-redundant logits + sibling exchange ----------------
// Grid 256 = (b = bx&63, hq = bx>>6). Phase 1: block computes ONLY its 32 logits
// (t in [hq*32, hq*32+32)) -> LDS + LLC (agent-scope stores). Publish flag, then wait for
// the 3 sibling blocks (same b), read their 96 logits from LLC. Softmax + weighted-sum
// slice as in round-5 attnsum_k. Publish-before-wait => deadlock-free; 256 blocks co-resident.
__global__ __launch_bounds__(1024) void attn2(
    const float* __restrict__ h_dec,           // [64,1024] fp32
    const __hip_bfloat16* __restrict__ proj,   // [64,128,1024] bf16
    float* __restrict__ logits_g,              // [64,128] f32 scratch (LLC-shared)
    __hip_bfloat16* __restrict__ Z,            // attn -> Z[b*2048 + 0..1023]
    unsigned int* __restrict__ flags,          // [256], zeroed at call start
    unsigned int want,
    float* __restrict__ aw_out) {              // null or [64,128]
    __shared__ float lsm[TT];
    __shared__ float red[2];
    __shared__ float osum[32 * 264];           // [tg][264] padded
    int bx = blockIdx.x;
    int b = bx & 63, hq = bx >> 6;
    int tid = threadIdx.x, wave = tid >> 6, lane = tid & 63;

    float hreg[16];
    const float* hp = h_dec + (long long)b * HH + lane * 16;
    #pragma unroll
    for (int j = 0; j < 16; j++) hreg[j] = hp[j];

    const __hip_bfloat16* pb = proj + (long long)b * TT * HH + lane * 16;
    const float scale = 0.03125f;  // 1/sqrt(1024)

    // ---- phase 1: this block's 32 logits (wave w -> 2 t's) ----
    #pragma unroll
    for (int it = 0; it < 2; it++) {
        int t = hq * 32 + wave * 2 + it;
        const __hip_bfloat16* p = pb + (long long)t * HH;
        bf16x8 p0 = *(const bf16x8*)(p);
        bf16x8 p1 = *(const bf16x8*)(p + 8);
        float dot = 0.f;
        #pragma unroll
        for (int j = 0; j < 8; j++) dot += hreg[j] * b2f(p0[j]) + hreg[8 + j] * b2f(p1[j]);
        #pragma unroll
        for (int off = 32; off; off >>= 1) dot += __shfl_xor(dot, off, 64);
        if (lane == 0) {
            float lv = dot * scale;
            lsm[t] = lv;
            __hip_atomic_store((float*)&logits_g[b * TT + t], lv,
                               __ATOMIC_RELAXED, __HIP_MEMORY_SCOPE_AGENT);
        }
    }
    __syncthreads();   // drains all lanes' stores (compiler emits vmcnt(0) before barrier)

    // ---- publish, then wait for siblings ----
    if (tid == 0)
        __hip_atomic_store(&flags[bx], want, __ATOMIC_RELEASE, __HIP_MEMORY_SCOPE_AGENT);
    if (tid < 3) {
        int q2 = (hq + 1 + tid) & 3;
        const unsigned int* fp = flags + b + 64 * q2;
        while (__hip_atomic_load(fp, __ATOMIC_ACQUIRE, __HIP_MEMORY_SCOPE_AGENT) < want)
            __builtin_amdgcn_s_sleep(1);
    }
    __syncthreads();

    // ---- import foreign logits ----
    if (tid < TT && (tid >> 5) != hq)
        lsm[tid] = __hip_atomic_load((const float*)&logits_g[b * TT + tid],
                                     __ATOMIC_RELAXED, __HIP_MEMORY_SCOPE_AGENT);
    __syncthreads();

    // ---- softmax reduce (wave 0) ----
    if (wave == 0) {
        float a = lsm[lane], c2 = lsm[lane + 64];
        float mx = fmaxf(a, c2);
        #pragma unroll
        for (int off = 32; off; off >>= 1) mx = fmaxf(mx, __shfl_xor(mx, off, 64));
        float s = __expf(a - mx) + __expf(c2 - mx);
        #pragma unroll
        for (int off = 32; off; off >>= 1) s += __shfl_xor(s, off, 64);
        if (lane == 0) { red[0] = mx; red[1] = s; }
    }
    __syncthreads();
    float mstar = red[0], invL = 1.f / red[1];

    // ---- weighted sum for this block's 256-col slice ----
    int hw = tid & 31, tg = tid >> 5;
    const __hip_bfloat16* base = proj + (long long)b * TT * HH + hq * 256 + hw * 8;
    float o8[8];
    #pragma unroll
    for (int j = 0; j < 8; j++) o8[j] = 0.f;
    #pragma unroll
    for (int k = 0; k < 4; k++) {
        int t = tg + k * 32;
        float w = __expf(lsm[t] - mstar) * invL;
        bf16x8 p = *(const bf16x8*)(base + (long long)t * HH);
        #pragma unroll
        for (int j = 0; j < 8; j++) o8[j] += w * b2f(p[j]);
    }
    #pragma unroll
    for (int j = 0; j < 8; j++) osum[tg * 264 + hw * 8 + j] = o8[j];
    __syncthreads();

    if (tid < 256) {
        float s = 0.f;
        #pragma unroll
        for (int g2 = 0; g2 < 32; g2++) s += osum[g2 * 264 + tid];
        Z[(long long)b * KD + hq * 256 + tid] = __float2bfloat16(s);
    }
    if (aw_out && hq == 0 && tid < TT)
        aw_out[(long long)b * TT + tid] = __expf(lsm[tid] - mstar) * invL;
}

// ---------------- host ----------------

extern "C" void kernel_launch(void* const* d_in, const int* in_sizes, int n_in,
                              void* d_out, int out_size, void* d_ws, size_t ws_size,
                              hipStream_t stream) {
    const float* x    = (const float*)d_in[0];
    const float* eWih = (const float*)d_in[1];
    const float* eWhh = (const float*)d_in[2];
    const float* ebih = (const float*)d_in[3];
    const float* ebhh = (const float*)d_in[4];
    const float* We2d = (const float*)d_in[5];
    const float* be2d = (const float*)d_in[6];
    const float* Wd2e = (const float*)d_in[7];
    const float* bd2e = (const float*)d_in[8];
    const float* dWih = (const float*)d_in[9];
    const float* dWhh = (const float*)d_in[10];
    const float* dbih = (const float*)d_in[11];
    const float* dbhh = (const float*)d_in[12];
    const float* Wc   = (const float*)d_in[13];
    const float* bc   = (const float*)d_in[14];

    float* scores = (float*)d_out;                  // [B,T,C]
    float* aw_out = scores + (size_t)BB * TT * CC;  // [B,T]

    char* ws = (char*)d_ws;
    size_t off = 0;
    auto alloc = [&](size_t bytes) -> char* {
        char* p = ws + off;
        off = (off + bytes + 255) & ~(size_t)255;
        return p;
    };

    // -------- tight, lifetime-aliased workspace layout (~119 MiB + optional xB) --------
    __hip_bfloat16* Xg    = (__hip_bfloat16*)alloc((size_t)BT * G4 * 2);   // 64 MiB, enc Xg then dec Xg
    char*           Bz    = alloc((size_t)G4 * KD * 2);                    // 16 MiB: eWhhB then Wz
    char*           Cp    = alloc((size_t)G4 * FF * 2);                    // 16 MiB: eWihB -> dWxB -> proj
    __hip_bfloat16* hts   = (__hip_bfloat16*)alloc((size_t)BT * HH * 2);   // 16 MiB: hts then hdts
    __hip_bfloat16* Wd2eT = (__hip_bfloat16*)alloc((size_t)HH * HH * 2);   // 2 MiB
    __hip_bfloat16* We2dB = (__hip_bfloat16*)alloc((size_t)HH * HH * 2);   // 2 MiB
    __hip_bfloat16* WcP   = (__hip_bfloat16*)alloc((size_t)128 * HH * 2);  // 256 KiB
    float*          encb  = (float*)alloc((size_t)G4 * 4);
    float*          badd  = (float*)alloc((size_t)G4 * 4);
    float*          bcP   = (float*)alloc((size_t)128 * 4);
    // state: cenc | cdec | hdec | henc0 | henc1 | Zbuf0 | Zbuf1 | logits_g | flags (all zeroed)
    char*           state = alloc(1572864 + 32768 + 1024);
    float*          cenc = (float*)(state);
    float*          cdec = (float*)(state + 262144);
    float*          hdec = (float*)(state + 524288);
    __hip_bfloat16* he0  = (__hip_bfloat16*)(state + 786432);
    __hip_bfloat16* he1  = (__hip_bfloat16*)(state + 917504);
    __hip_bfloat16* Zb0  = (__hip_bfloat16*)(state + 1048576);
    __hip_bfloat16* Zb1  = (__hip_bfloat16*)(state + 1310720);
    float*          logits_g = (float*)(state + 1572864);
    unsigned int*   dflags   = (unsigned int*)(state + 1572864 + 32768);

    __hip_bfloat16* eWhhB = (__hip_bfloat16*)Bz;     // encoder phase
    __hip_bfloat16* Wz    = (__hip_bfloat16*)Bz;     // decoder phase (overwrites)
    __hip_bfloat16* eWihB = (__hip_bfloat16*)Cp;     // phase 1
    __hip_bfloat16* dWxB  = (__hip_bfloat16*)Cp;     // phase 2
    __hip_bfloat16* proj  = (__hip_bfloat16*)Cp;     // phase 3
    __hip_bfloat16* hdts  = hts;                     // decoder phase

    (void)in_sizes; (void)n_in;

    if (off > ws_size) {
        long long n = out_size;
        fill_f32<<<dim3((unsigned)((n + 255) / 256)), 256, 0, stream>>>((float*)d_out, n, 111.0f);
        return;
    }

    // optional bf16 copy of x (32 MiB) — only if workspace allows
    __hip_bfloat16* xB = nullptr;
    if (off + (size_t)BT * FF * 2 <= ws_size) {
        xB = (__hip_bfloat16*)(ws + off);
    }

    auto packGrid = [](long long tot) { return dim3((unsigned)((tot + 255) / 256)); };

    // ---- setup ----
    zero_u32<<<dim3(1569), dim3(256), 0, stream>>>((unsigned int*)state, 401664LL);
    pack_bf16<<<packGrid((long long)G4 * FF), 256, 0, stream>>>(eWih, FF, 0, eWihB, FF, G4, FF, G4);
    pack_bf16<<<packGrid((long long)G4 * HH), 256, 0, stream>>>(eWhh, HH, 0, eWhhB, HH, G4, HH, G4);
    packT_bf16<<<packGrid((long long)HH * HH), 256, 0, stream>>>(Wd2e, HH, HH, Wd2eT);
    pack_bf16<<<packGrid((long long)HH * HH), 256, 0, stream>>>(We2d, HH, 0, We2dB, HH, HH, HH, HH);
    pack_bf16<<<packGrid((long long)128 * HH), 256, 0, stream>>>(Wc, HH, 0, WcP, HH, 128, HH, CC);
    add_bias2<<<16, 256, 0, stream>>>(ebih, ebhh, encb, G4);
    pad_bias<<<1, 128, 0, stream>>>(bc, bcP, CC, 128);
    bcomb_kernel<<<G4, 64, 0, stream>>>(dWih, bd2e, dbih, dbhh, badd);
    if (xB)
        pack_bf16<<<packGrid((long long)BT * FF), 256, 0, stream>>>(x, FF, 0, xB, FF, BT, FF, BT);

    // enc Xg = bf16(x @ enc_Wih^T + (bih+bhh))   [B,T,4H]
    if (xB)
        gemm_tile<FF, false><<<dim3(BT / 128, G4 / 128), 256, 0, stream>>>(
            xB, FF, eWihB, encb, Xg, 1, G4, G4);
    else
        gemm_tile<FF, true><<<dim3(BT / 128, G4 / 128), 256, 0, stream>>>(
            x, FF, eWihB, encb, Xg, 1, G4, G4);

    // ---- encoder recurrence (one fused kernel per step, h ping-pong, 256 blocks) ----
    for (int t = 0; t < TT; t++) {
        __hip_bfloat16* hin  = (t & 1) ? he1 : he0;
        __hip_bfloat16* hout = (t & 1) ? he0 : he1;
        fused_step<HH><<<dim3(256), dim3(1024), 0, stream>>>(
            hin, eWhhB, Xg + (size_t)t * G4, (long long)TT * G4,
            cenc, nullptr, hout, HH, hts + (size_t)t * HH, (long long)TT * HH);
    }

    // dec Xg = bf16(x @ dec_Wih[:, :F]^T + (dbih+dbhh+b_comb))  (Cp: eWihB -> dWxB)
    pack_bf16<<<packGrid((long long)G4 * FF), 256, 0, stream>>>(dWih, FF + HH, 0, dWxB, FF, G4, FF, G4);
    if (xB)
        gemm_tile<FF, false><<<dim3(BT / 128, G4 / 128), 256, 0, stream>>>(
            xB, FF, dWxB, badd, Xg, 1, G4, G4);
    else
        gemm_tile<FF, true><<<dim3(BT / 128, G4 / 128), 256, 0, stream>>>(
            x, FF, dWxB, badd, Xg, 1, G4, G4);

    // Wz[:, 0:1024] = dec_Wih[:, F:] @ Wd2e  (A read fp32 directly, lda = F+H)
    gemm_tile<HH, true><<<dim3(G4 / 128, HH / 128), 256, 0, stream>>>(
        dWih + FF, FF + HH, Wd2eT, nullptr, Wz, 1, KD, HH);
    // Wz[:, 1024:2048] = dec_Whh
    pack_bf16<<<packGrid((long long)G4 * HH), 256, 0, stream>>>(dWhh, HH, 0, Wz + HH, KD, G4, HH, G4);

    // proj = h_ts @ We2d^T + be2d  (bf16 out; Cp: dWxB -> proj)
    gemm_tile<HH, false><<<dim3(BT / 128, HH / 128), 256, 0, stream>>>(
        hts, HH, We2dB, be2d, proj, 1, HH, HH);

    // ---- decoder recurrence: attn2 (1 dispatch, sibling flag exchange) + gates ----
    for (int t = 0; t < TT; t++) {
        __hip_bfloat16* Zin  = (t & 1) ? Zb1 : Zb0;
        __hip_bfloat16* Znxt = (t & 1) ? Zb0 : Zb1;
        attn2<<<dim3(256), dim3(1024), 0, stream>>>(
            hdec, proj, logits_g, Zin, dflags, (unsigned)(t + 1),
            (t == TT - 1) ? aw_out : nullptr);
        fused_step<KD><<<dim3(256), dim3(1024), 0, stream>>>(
            Zin, Wz, Xg + (size_t)t * G4, (long long)TT * G4,
            cdec, hdec, Znxt + HH, KD, hdts + (size_t)t * HH, (long long)TT * HH);
    }

    // scores = h_dec_ts @ Wc^T + bc   (N padded to 128, store n<22, ldc=22)
    gemm_tile<HH, false><<<dim3(BT / 128, 1), 256, 0, stream>>>(
        hdts, HH, WcP, bcP, scores, 0, CC, CC);
}

// Round 8
// 5935.624 us; speedup vs baseline: 1.1521x; 1.1521x over previous
//
#include <hip/hip_runtime.h>
#include <hip/hip_bf16.h>

#define BB 64
#define TT 128
#define FF 2048
#define HH 1024
#define CC 22
#define G4 4096      // 4*H
#define KD 2048      // decoder Z inner dim (attn | h)
#define BT 8192      // B*T

typedef __attribute__((ext_vector_type(8))) short bf16x8;
typedef __attribute__((ext_vector_type(4))) float f32x4;

__device__ __forceinline__ f32x4 mfma16(bf16x8 a, bf16x8 b, f32x4 c) {
    return __builtin_amdgcn_mfma_f32_16x16x32_bf16(a, b, c, 0, 0, 0);
}

__device__ __forceinline__ float b2f(short s) {
    unsigned int u = ((unsigned int)(unsigned short)s) << 16;
    union { unsigned int i; float f; } x; x.i = u; return x.f;
}

__device__ __forceinline__ short f2bs(float f) {
    union { __hip_bfloat16 h; short s; } u;
    u.h = __float2bfloat16(f);
    return u.s;
}

// ---------------- utility kernels ----------------

__global__ void zero_u32(unsigned int* p, long long n) {
    long long i = (long long)blockIdx.x * 256 + threadIdx.x;
    if (i < n) p[i] = 0u;
}

__global__ void fill_f32(float* p, long long n, float v) {
    long long i = (long long)blockIdx.x * 256 + threadIdx.x;
    if (i < n) p[i] = v;
}

// dst[r*dld + c] = bf16(src[r*sld + soff + c]) for r < valid, else 0
__global__ void pack_bf16(const float* __restrict__ src, long long sld, long long soff,
                          __hip_bfloat16* __restrict__ dst, long long dld,
                          int rows, int cols, int valid) {
    long long i = (long long)blockIdx.x * 256 + threadIdx.x;
    long long tot = (long long)rows * cols;
    if (i >= tot) return;
    int r = (int)(i / cols), c = (int)(i % cols);
    float v = (r < valid) ? src[(long long)r * sld + soff + c] : 0.f;
    dst[(long long)r * dld + c] = __float2bfloat16(v);
}

// dst[c*R + r] = bf16(src[r*C + c])   (transpose-convert)
__global__ void packT_bf16(const float* __restrict__ src, int R, int Ccols,
                           __hip_bfloat16* __restrict__ dst) {
    long long i = (long long)blockIdx.x * 256 + threadIdx.x;
    long long tot = (long long)R * Ccols;
    if (i >= tot) return;
    int r = (int)(i / Ccols), c = (int)(i % Ccols);
    dst[(long long)c * R + r] = __float2bfloat16(src[i]);
}

__global__ void add_bias2(const float* a, const float* b, float* out, int n) {
    int i = blockIdx.x * 256 + threadIdx.x;
    if (i < n) out[i] = a[i] + b[i];
}

__global__ void pad_bias(const float* src, float* dst, int nsrc, int ndst) {
    int i = blockIdx.x * blockDim.x + threadIdx.x;
    if (i < ndst) dst[i] = (i < nsrc) ? src[i] : 0.f;
}

// badd[r] = dbih[r] + dbhh[r] + dot(dec_Wih[r, F:F+H], bd2e)
__global__ __launch_bounds__(64) void bcomb_kernel(const float* __restrict__ dWih,
                                                   const float* __restrict__ bd2e,
                                                   const float* __restrict__ dbih,
                                                   const float* __restrict__ dbhh,
                                                   float* __restrict__ badd) {
    int r = blockIdx.x, lane = threadIdx.x;
    const float* row = dWih + (long long)r * (FF + HH) + FF;
    float s = 0.f;
    for (int k = lane; k < HH; k += 64) s += row[k] * bd2e[k];
    #pragma unroll
    for (int off = 32; off; off >>= 1) s += __shfl_xor(s, off, 64);
    if (lane == 0) badd[r] = s + dbih[r] + dbhh[r];
}

// ---------------- MFMA GEMM: C[M,N] = A[M,K] @ W[N,K]^T (+bias) ----------------
// block = 256 thr (4 waves), block tile 128x128, wave tile 64x64 (4x4 of 16x16).
// AF32: A is fp32 with leading dim lda, vector-loaded (float4 x2) and converted.
template <int K, bool AF32>
__global__ __launch_bounds__(256) void gemm_tile(
    const void* __restrict__ Aptr, long long lda,
    const __hip_bfloat16* __restrict__ W,
    const float* __restrict__ bias, void* __restrict__ Cout, int out_bf16,
    long long ldc, int n_store) {
    int tid = threadIdx.x;
    int wave = tid >> 6, lane = tid & 63;
    int wm = wave >> 1, wn = wave & 1;
    int m_base = blockIdx.x * 128 + wm * 64;
    int n_base = blockIdx.y * 128 + wn * 64;
    int row_in = lane & 15, k8 = (lane >> 4) * 8;

    f32x4 acc[4][4] = {};
    const float* Af = (const float*)Aptr + (long long)(m_base + row_in) * lda + k8;
    const __hip_bfloat16* Ab = (const __hip_bfloat16*)Aptr + (long long)(m_base + row_in) * lda + k8;
    const __hip_bfloat16* Wp = W + (long long)(n_base + row_in) * K + k8;

    #pragma unroll 2
    for (int k0 = 0; k0 < K; k0 += 32) {
        bf16x8 a[4], b[4];
        #pragma unroll
        for (int i = 0; i < 4; i++) {
            if (AF32) {
                const float* p = Af + (long long)i * 16 * lda + k0;
                const float4 f0 = *(const float4*)(p);
                const float4 f1 = *(const float4*)(p + 4);
                a[i][0] = f2bs(f0.x); a[i][1] = f2bs(f0.y);
                a[i][2] = f2bs(f0.z); a[i][3] = f2bs(f0.w);
                a[i][4] = f2bs(f1.x); a[i][5] = f2bs(f1.y);
                a[i][6] = f2bs(f1.z); a[i][7] = f2bs(f1.w);
            } else {
                a[i] = *(const bf16x8*)(Ab + (long long)i * 16 * lda + k0);
            }
        }
        #pragma unroll
        for (int i = 0; i < 4; i++) b[i] = *(const bf16x8*)(Wp + (long long)i * 16 * K + k0);
        #pragma unroll
        for (int mt = 0; mt < 4; mt++)
            #pragma unroll
            for (int nt = 0; nt < 4; nt++)
                acc[mt][nt] = mfma16(a[mt], b[nt], acc[mt][nt]);
    }

    int col = lane & 15, rowq = (lane >> 4) * 4;
    #pragma unroll
    for (int mt = 0; mt < 4; mt++)
        #pragma unroll
        for (int nt = 0; nt < 4; nt++) {
            int n = n_base + nt * 16 + col;
            if (n >= n_store) continue;
            float bv = bias ? bias[n] : 0.f;
            #pragma unroll
            for (int r = 0; r < 4; r++) {
                long long m = m_base + mt * 16 + rowq + r;
                float v = acc[mt][nt][r] + bv;
                if (out_bf16) ((__hip_bfloat16*)Cout)[m * ldc + n] = __float2bfloat16(v);
                else          ((float*)Cout)[m * ldc + n] = v;
            }
        }
}

// ---------------- fused gates GEMM + LSTM cell update ----------------
// Grid: 256 blocks = 64 hh-tiles x 4 batch-quarters; block 1024 thr = 16 waves = 4g x 4ks.
// Wave: 16x16 MFMA tile over K/4; partials reduced through LDS; 256 epilogue threads.
// Reads Z (prev h) and writes new h -> caller MUST ping-pong h/Z buffers.
template <int KZ>
__global__ __launch_bounds__(1024) void fused_step(
    const __hip_bfloat16* __restrict__ Z,        // [64, KZ]
    const __hip_bfloat16* __restrict__ W,        // [4096, KZ]
    const __hip_bfloat16* __restrict__ Xg_t, long long xg_stride,
    float* __restrict__ c,
    float* __restrict__ h_f32,
    __hip_bfloat16* __restrict__ hb_a, long long stride_a,
    __hip_bfloat16* __restrict__ hb_b, long long stride_b) {
    constexpr int KQ = KZ / 4;
    __shared__ float P[16 * 256];
    int tid = threadIdx.x;
    int wave = tid >> 6, lane = tid & 63;
    int g = wave >> 2, ks = wave & 3;
    int hh_t = blockIdx.x & 63, mb = blockIdx.x >> 6;
    int m_base = mb * 16;
    int hh0 = hh_t * 16;
    int n0 = g * HH + hh0;
    int row_in = lane & 15, k8 = (lane >> 4) * 8;
    long long koff = (long long)ks * KQ + k8;

    const __hip_bfloat16* Ap = Z + (long long)(m_base + row_in) * KZ + koff;
    const __hip_bfloat16* Wp = W + (long long)(n0 + row_in) * KZ + koff;

    f32x4 acc = {};
    #pragma unroll 8
    for (int k0 = 0; k0 < KQ; k0 += 32) {
        bf16x8 bw = *(const bf16x8*)(Wp + k0);
        bf16x8 a0 = *(const bf16x8*)(Ap + k0);
        acc = mfma16(a0, bw, acc);
    }

    int col = lane & 15, rowq = (lane >> 4) * 4;
    #pragma unroll
    for (int r = 0; r < 4; r++)
        P[wave * 256 + (rowq + r) * 16 + col] = acc[r];
    __syncthreads();

    if (tid < 256) {
        int bl = tid >> 4, hl = tid & 15;
        int bb = m_base + bl, hh = hh0 + hl;
        float gv[4];
        #pragma unroll
        for (int gg2 = 0; gg2 < 4; gg2++) {
            float s = 0.f;
            #pragma unroll
            for (int kk = 0; kk < 4; kk++) s += P[(gg2 * 4 + kk) * 256 + tid];
            gv[gg2] = s + __bfloat162float(Xg_t[(long long)bb * xg_stride + gg2 * HH + hh]);
        }
        float si = 1.f / (1.f + __expf(-gv[0]));
        float sf = 1.f / (1.f + __expf(-gv[1]));
        float tg = tanhf(gv[2]);
        float so = 1.f / (1.f + __expf(-gv[3]));
        long long idx = (long long)bb * HH + hh;
        float cn = sf * c[idx] + si * tg;
        c[idx] = cn;
        float hn = so * tanhf(cn);
        if (h_f32) h_f32[idx] = hn;
        __hip_bfloat16 hb = __float2bfloat16(hn);
        hb_a[(long long)bb * stride_a + hh] = hb;
        hb_b[(long long)bb * stride_b + hh] = hb;
    }
}

// ---------------- attention, stage 1: logits (full machine) ----------------
// Grid 256 = (b = bx&63, tq = bx>>6). Block 1024 thr = 16 waves; wave computes 2 t's.
// logits_g[b*128+t] = scale * <hdec[b], proj[b][t]>
__global__ __launch_bounds__(1024) void logits_k(
    const float* __restrict__ h_dec,           // [64,1024] fp32
    const __hip_bfloat16* __restrict__ proj,   // [64,128,1024] bf16
    float* __restrict__ logits_g) {            // [64,128] f32
    int bx = blockIdx.x;
    int b = bx & 63, tq = bx >> 6;
    int tid = threadIdx.x, wave = tid >> 6, lane = tid & 63;

    float hreg[16];
    const float* hp = h_dec + (long long)b * HH + lane * 16;
    #pragma unroll
    for (int j = 0; j < 16; j++) hreg[j] = hp[j];

    const __hip_bfloat16* pb = proj + (long long)b * TT * HH + lane * 16;
    const float scale = 0.03125f;  // 1/sqrt(1024)

    #pragma unroll
    for (int it = 0; it < 2; it++) {
        int t = tq * 32 + wave * 2 + it;
        const __hip_bfloat16* p = pb + (long long)t * HH;
        bf16x8 p0 = *(const bf16x8*)(p);
        bf16x8 p1 = *(const bf16x8*)(p + 8);
        float dot = 0.f;
        #pragma unroll
        for (int j = 0; j < 8; j++) dot += hreg[j] * b2f(p0[j]) + hreg[8 + j] * b2f(p1[j]);
        #pragma unroll
        for (int off = 32; off; off >>= 1) dot += __shfl_xor(dot, off, 64);
        if (lane == 0) logits_g[b * TT + t] = dot * scale;
    }
}

// ---------------- attention, stage 2: softmax + weighted sum (full machine) ----------------
// Grid 256 = (b = bx&63, hq = bx>>6). Block computes Z[b][hq*256 .. +256).
// Thread (hw = tid&31, tg = tid>>5): o8 partial over 4 t's, LDS tree over 32 tg.
__global__ __launch_bounds__(1024) void attnsum_k(
    const float* __restrict__ logits_g,        // [64,128] f32
    const __hip_bfloat16* __restrict__ proj,   // [64,128,1024] bf16
    __hip_bfloat16* __restrict__ Z,            // attn -> Z[b*2048 + 0..1023]
    float* __restrict__ aw_out) {              // null or [64,128]
    __shared__ float lsm[TT];
    __shared__ float red[2];
    __shared__ float osum[32 * 264];           // [tg][264] padded
    int bx = blockIdx.x;
    int b = bx & 63, hq = bx >> 6;
    int tid = threadIdx.x, wave = tid >> 6, lane = tid & 63;

    if (tid < TT) lsm[tid] = logits_g[b * TT + tid];
    __syncthreads();

    if (wave == 0) {
        float a = lsm[lane], c2 = lsm[lane + 64];
        float mx = fmaxf(a, c2);
        #pragma unroll
        for (int off = 32; off; off >>= 1) mx = fmaxf(mx, __shfl_xor(mx, off, 64));
        float s = __expf(a - mx) + __expf(c2 - mx);
        #pragma unroll
        for (int off = 32; off; off >>= 1) s += __shfl_xor(s, off, 64);
        if (lane == 0) { red[0] = mx; red[1] = s; }
    }
    __syncthreads();
    float mstar = red[0], invL = 1.f / red[1];

    int hw = tid & 31, tg = tid >> 5;
    const __hip_bfloat16* base = proj + (long long)b * TT * HH + hq * 256 + hw * 8;
    float o8[8];
    #pragma unroll
    for (int j = 0; j < 8; j++) o8[j] = 0.f;
    #pragma unroll
    for (int k = 0; k < 4; k++) {
        int t = tg + k * 32;
        float w = __expf(lsm[t] - mstar) * invL;
        bf16x8 p = *(const bf16x8*)(base + (long long)t * HH);
        #pragma unroll
        for (int j = 0; j < 8; j++) o8[j] += w * b2f(p[j]);
    }
    #pragma unroll
    for (int j = 0; j < 8; j++) osum[tg * 264 + hw * 8 + j] = o8[j];
    __syncthreads();

    if (tid < 256) {
        float s = 0.f;
        #pragma unroll
        for (int g2 = 0; g2 < 32; g2++) s += osum[g2 * 264 + tid];
        Z[(long long)b * KD + hq * 256 + tid] = __float2bfloat16(s);
    }
    if (aw_out && hq == 0 && tid < TT)
        aw_out[(long long)b * TT + tid] = __expf(lsm[tid] - mstar) * invL;
}

// ---------------- host ----------------

extern "C" void kernel_launch(void* const* d_in, const int* in_sizes, int n_in,
                              void* d_out, int out_size, void* d_ws, size_t ws_size,
                              hipStream_t stream) {
    const float* x    = (const float*)d_in[0];
    const float* eWih = (const float*)d_in[1];
    const float* eWhh = (const float*)d_in[2];
    const float* ebih = (const float*)d_in[3];
    const float* ebhh = (const float*)d_in[4];
    const float* We2d = (const float*)d_in[5];
    const float* be2d = (const float*)d_in[6];
    const float* Wd2e = (const float*)d_in[7];
    const float* bd2e = (const float*)d_in[8];
    const float* dWih = (const float*)d_in[9];
    const float* dWhh = (const float*)d_in[10];
    const float* dbih = (const float*)d_in[11];
    const float* dbhh = (const float*)d_in[12];
    const float* Wc   = (const float*)d_in[13];
    const float* bc   = (const float*)d_in[14];

    float* scores = (float*)d_out;                  // [B,T,C]
    float* aw_out = scores + (size_t)BB * TT * CC;  // [B,T]

    char* ws = (char*)d_ws;
    size_t off = 0;
    auto alloc = [&](size_t bytes) -> char* {
        char* p = ws + off;
        off = (off + bytes + 255) & ~(size_t)255;
        return p;
    };

    // -------- tight, lifetime-aliased workspace layout (~119 MiB + optional xB) --------
    __hip_bfloat16* Xg    = (__hip_bfloat16*)alloc((size_t)BT * G4 * 2);   // 64 MiB, enc Xg then dec Xg
    char*           Bz    = alloc((size_t)G4 * KD * 2);                    // 16 MiB: eWhhB then Wz
    char*           Cp    = alloc((size_t)G4 * FF * 2);                    // 16 MiB: eWihB -> dWxB -> proj
    __hip_bfloat16* hts   = (__hip_bfloat16*)alloc((size_t)BT * HH * 2);   // 16 MiB: hts then hdts
    __hip_bfloat16* Wd2eT = (__hip_bfloat16*)alloc((size_t)HH * HH * 2);   // 2 MiB
    __hip_bfloat16* We2dB = (__hip_bfloat16*)alloc((size_t)HH * HH * 2);   // 2 MiB
    __hip_bfloat16* WcP   = (__hip_bfloat16*)alloc((size_t)128 * HH * 2);  // 256 KiB
    float*          encb  = (float*)alloc((size_t)G4 * 4);
    float*          badd  = (float*)alloc((size_t)G4 * 4);
    float*          bcP   = (float*)alloc((size_t)128 * 4);
    // state: cenc | cdec | hdec | henc0 | henc1 | Zbuf0 | Zbuf1 (zeroed) | logits_g
    char*           state = alloc(1572864 + 32768);
    float*          cenc = (float*)(state);
    float*          cdec = (float*)(state + 262144);
    float*          hdec = (float*)(state + 524288);
    __hip_bfloat16* he0  = (__hip_bfloat16*)(state + 786432);
    __hip_bfloat16* he1  = (__hip_bfloat16*)(state + 917504);
    __hip_bfloat16* Zb0  = (__hip_bfloat16*)(state + 1048576);
    __hip_bfloat16* Zb1  = (__hip_bfloat16*)(state + 1310720);
    float*          logits_g = (float*)(state + 1572864);

    __hip_bfloat16* eWhhB = (__hip_bfloat16*)Bz;     // encoder phase
    __hip_bfloat16* Wz    = (__hip_bfloat16*)Bz;     // decoder phase (overwrites)
    __hip_bfloat16* eWihB = (__hip_bfloat16*)Cp;     // phase 1
    __hip_bfloat16* dWxB  = (__hip_bfloat16*)Cp;     // phase 2
    __hip_bfloat16* proj  = (__hip_bfloat16*)Cp;     // phase 3
    __hip_bfloat16* hdts  = hts;                     // decoder phase

    (void)in_sizes; (void)n_in;

    if (off > ws_size) {
        long long n = out_size;
        fill_f32<<<dim3((unsigned)((n + 255) / 256)), 256, 0, stream>>>((float*)d_out, n, 111.0f);
        return;
    }

    // optional bf16 copy of x (32 MiB) — only if workspace allows (verified path, round 7)
    __hip_bfloat16* xB = nullptr;
    if (off + (size_t)BT * FF * 2 <= ws_size) {
        xB = (__hip_bfloat16*)(ws + off);
    }

    auto packGrid = [](long long tot) { return dim3((unsigned)((tot + 255) / 256)); };

    // ---- setup ----
    zero_u32<<<dim3(1536), dim3(256), 0, stream>>>((unsigned int*)state, 393216LL);
    pack_bf16<<<packGrid((long long)G4 * FF), 256, 0, stream>>>(eWih, FF, 0, eWihB, FF, G4, FF, G4);
    pack_bf16<<<packGrid((long long)G4 * HH), 256, 0, stream>>>(eWhh, HH, 0, eWhhB, HH, G4, HH, G4);
    packT_bf16<<<packGrid((long long)HH * HH), 256, 0, stream>>>(Wd2e, HH, HH, Wd2eT);
    pack_bf16<<<packGrid((long long)HH * HH), 256, 0, stream>>>(We2d, HH, 0, We2dB, HH, HH, HH, HH);
    pack_bf16<<<packGrid((long long)128 * HH), 256, 0, stream>>>(Wc, HH, 0, WcP, HH, 128, HH, CC);
    add_bias2<<<16, 256, 0, stream>>>(ebih, ebhh, encb, G4);
    pad_bias<<<1, 128, 0, stream>>>(bc, bcP, CC, 128);
    bcomb_kernel<<<G4, 64, 0, stream>>>(dWih, bd2e, dbih, dbhh, badd);
    if (xB)
        pack_bf16<<<packGrid((long long)BT * FF), 256, 0, stream>>>(x, FF, 0, xB, FF, BT, FF, BT);

    // enc Xg = bf16(x @ enc_Wih^T + (bih+bhh))   [B,T,4H]
    if (xB)
        gemm_tile<FF, false><<<dim3(BT / 128, G4 / 128), 256, 0, stream>>>(
            xB, FF, eWihB, encb, Xg, 1, G4, G4);
    else
        gemm_tile<FF, true><<<dim3(BT / 128, G4 / 128), 256, 0, stream>>>(
            x, FF, eWihB, encb, Xg, 1, G4, G4);

    // ---- encoder recurrence (one fused kernel per step, h ping-pong, 256 blocks) ----
    for (int t = 0; t < TT; t++) {
        __hip_bfloat16* hin  = (t & 1) ? he1 : he0;
        __hip_bfloat16* hout = (t & 1) ? he0 : he1;
        fused_step<HH><<<dim3(256), dim3(1024), 0, stream>>>(
            hin, eWhhB, Xg + (size_t)t * G4, (long long)TT * G4,
            cenc, nullptr, hout, HH, hts + (size_t)t * HH, (long long)TT * HH);
    }

    // dec Xg = bf16(x @ dec_Wih[:, :F]^T + (dbih+dbhh+b_comb))  (Cp: eWihB -> dWxB)
    pack_bf16<<<packGrid((long long)G4 * FF), 256, 0, stream>>>(dWih, FF + HH, 0, dWxB, FF, G4, FF, G4);
    if (xB)
        gemm_tile<FF, false><<<dim3(BT / 128, G4 / 128), 256, 0, stream>>>(
            xB, FF, dWxB, badd, Xg, 1, G4, G4);
    else
        gemm_tile<FF, true><<<dim3(BT / 128, G4 / 128), 256, 0, stream>>>(
            x, FF, dWxB, badd, Xg, 1, G4, G4);

    // Wz[:, 0:1024] = dec_Wih[:, F:] @ Wd2e  (A read fp32 directly, lda = F+H)
    gemm_tile<HH, true><<<dim3(G4 / 128, HH / 128), 256, 0, stream>>>(
        dWih + FF, FF + HH, Wd2eT, nullptr, Wz, 1, KD, HH);
    // Wz[:, 1024:2048] = dec_Whh
    pack_bf16<<<packGrid((long long)G4 * HH), 256, 0, stream>>>(dWhh, HH, 0, Wz + HH, KD, G4, HH, G4);

    // proj = h_ts @ We2d^T + be2d  (bf16 out; Cp: dWxB -> proj)
    gemm_tile<HH, false><<<dim3(BT / 128, HH / 128), 256, 0, stream>>>(
        hts, HH, We2dB, be2d, proj, 1, HH, HH);

    // ---- decoder recurrence: logits (full machine) + attnsum (full machine) + gates ----
    for (int t = 0; t < TT; t++) {
        __hip_bfloat16* Zin  = (t & 1) ? Zb1 : Zb0;
        __hip_bfloat16* Znxt = (t & 1) ? Zb0 : Zb1;
        logits_k<<<dim3(256), dim3(1024), 0, stream>>>(hdec, proj, logits_g);
        attnsum_k<<<dim3(256), dim3(1024), 0, stream>>>(
            logits_g, proj, Zin, (t == TT - 1) ? aw_out : nullptr);
        fused_step<KD><<<dim3(256), dim3(1024), 0, stream>>>(
            Zin, Wz, Xg + (size_t)t * G4, (long long)TT * G4,
            cdec, hdec, Znxt + HH, KD, hdts + (size_t)t * HH, (long long)TT * HH);
    }

    // scores = h_dec_ts @ Wc^T + bc   (N padded to 128, store n<22, ldc=22)
    gemm_tile<HH, false><<<dim3(BT / 128, 1), 256, 0, stream>>>(
        hdts, HH, WcP, bcP, scores, 0, CC, CC);
}